// Round 1
// 117.501 us; speedup vs baseline: 1.0070x; 1.0070x over previous
//
#include <hip/hip_runtime.h>

typedef unsigned short u16;
typedef unsigned int u32;

#define BB 8
#define CC 128
#define TT_ 1000
#define TPAD 1024
#define NB 31
#define MAXBW 16
#define MAXOC 128

typedef __bf16 bf16x8 __attribute__((ext_vector_type(8)));
typedef float f32x4 __attribute__((ext_vector_type(4)));

__device__ __forceinline__ u16 f2bf(float f) {
    u32 u = __float_as_uint(f);
    return (u16)((u + 0x7fffu + ((u >> 16) & 1u)) >> 16);
}
__device__ __forceinline__ float bf2f(u16 h) { return __uint_as_float(((u32)h) << 16); }
__device__ __forceinline__ int bandBW(int i) { return (i < 10) ? 3 : ((i < 22) ? 8 : ((i < 30) ? 16 : 3)); }
__device__ __forceinline__ int bandF0(int i) {
    return (i < 10) ? 3 * i : ((i < 22) ? 30 + 8 * (i - 10) : ((i < 30) ? 126 + 16 * (i - 22) : 254));
}
// Per-band channel permutation (K-dim permutation, applied to BOTH xt and wgT2;
// MFMA dot over K is permutation-invariant when both operands agree).
// Chosen so the kstat scatter-write is LDS-bank-conflict-free:
// bank = 4*((band>>2)^oct) + (((c>>1)&3)^(band&3)) -> distinct for all 31 bands.
__device__ __forceinline__ int bandSW(int i) { return ((i >> 2) << 3) | ((i & 3) << 1); }

// ==================== FULL PATH ====================

// kstat v6: transpose to xt[band][t(1024 pad)][cpos] bf16, cpos = c ^ sw(band).
// Block = (t-chunk of 4, b). LDS tile [31][4][128] u16 (31,744 B -> 5 blocks/CU).
// Write pass: all 16 float4 loads issued up-front (latency hiding), scatter
// ds_write_b16 with conflict-free per-band XOR swizzle.
// Store pass: LINEAR uint4 copy (permutation kept in global layout).
__global__ __launch_bounds__(256) void kstat(const float* __restrict__ x,
                                             u16* __restrict__ xt,
                                             float* __restrict__ partials,
                                             int b0) {
    const int q = blockIdx.x, bl = blockIdx.y, b = b0 + bl, tid = threadIdx.x;
    __shared__ __align__(16) u16 tile[NB * 512];   // 31,744 B
    const int t0 = q * 4;

    const float4* src4 = (const float4*)(x + (size_t)b * (CC * TT_ * NB));
    const int cbase = q * 31;

    // ---- write pass ----
    float4 v[16];
    #pragma unroll
    for (int s = 0; s < 16; ++s) {
        if (s < 15 || tid < 128) {              // 3968 = 15*256 + 128
            int idx = tid + s * 256;
            int c = idx / 31;
            int k = idx - c * 31;
            v[s] = src4[c * 7750 + cbase + k];
        }
    }
    #pragma unroll
    for (int s = 0; s < 16; ++s) {
        if (s < 15 || tid < 128) {
            int idx = tid + s * 256;
            int c = idx / 31;
            int k = idx - c * 31;
            int le = 4 * k;
            #pragma unroll
            for (int j = 0; j < 4; ++j) {
                int e = le + j;                 // 0..123 = tl*31 + band
                int tl = (e >= 93) ? 3 : ((e >= 62) ? 2 : ((e >= 31) ? 1 : 0));
                int band = e - tl * 31;
                int cp = c ^ bandSW(band);
                tile[(band * 4 + tl) * 128 + cp] = f2bf((&v[s].x)[j]);
            }
        }
    }
    __syncthreads();

    // ---- store pass: linear copy; per wave-instr one band's 4x256B = 1KB contiguous ----
    const uint4* t4 = (const uint4*)tile;       // chunk index: (band*4+tl)*16 + m
    uint4* dst4 = (uint4*)xt;
    for (int n = tid; n < 1984; n += 256) {     // 124 tasks * 16 chunks
        int task = n >> 4, m = n & 15;
        int band = task >> 2, tl = task & 3;
        uint4 u = t4[task * 16 + m];
        dst4[((size_t)(bl * NB + band) * TPAD + t0 + tl) * 16 + m] = u;
    }

    // ---- stats: 8 lanes/band, register accumulation, shfl reduce (order-invariant) ----
    if (tid < 248) {
        int band = tid >> 3, slot = tid & 7;
        float s = 0.f, sq = 0.f;
        #pragma unroll
        for (int r = 0; r < 8; ++r) {
            int tl = r >> 1, m = slot + 8 * (r & 1);
            uint4 u = t4[(band * 4 + tl) * 16 + m];
            #pragma unroll
            for (int w = 0; w < 4; ++w) {
                u32 uu = (&u.x)[w];
                float f0 = __uint_as_float(uu << 16);
                float f1 = __uint_as_float(uu & 0xffff0000u);
                s += f0 + f1;
                sq += f0 * f0 + f1 * f1;
            }
        }
        #pragma unroll
        for (int off = 1; off < 8; off <<= 1) {
            s  += __shfl_xor(s, off);
            sq += __shfl_xor(sq, off);
        }
        if (slot == 0) {
            *(float2*)&partials[((size_t)(b * NB + band) * 250 + q) * 2] = make_float2(s, sq);
        }
    }
}

// kfoldW v3: wb/wgs dot products + bf16 wgT2[band][oc(128)][cpos(128)] with the
// SAME per-band channel permutation cpos = c ^ sw(band) as xt (rows >= oc zeroed).
__global__ __launch_bounds__(128) void kfoldW(const float* __restrict__ w,
                                              const float* __restrict__ gamma,
                                              const float* __restrict__ beta,
                                              u16* __restrict__ wgT2,
                                              float* __restrict__ wbArr,
                                              float* __restrict__ wgsArr) {
    const int i = blockIdx.x, tid = threadIdx.x;
    __shared__ float g[CC], be[CC];
    g[tid] = gamma[i * CC + tid];
    be[tid] = beta[i * CC + tid];
    __syncthreads();
    const int oc = bandBW(i) * 8;
    // part 1: thread = output row o
    float wb = 0.f, wgs = 0.f;
    for (int c = 0; c < CC; ++c) {
        float wv = w[(size_t)(i * MAXOC + tid) * CC + c];
        wb += wv * be[c];
        wgs += wv * g[c];
    }
    wbArr[i * CC + tid] = wb;
    wgsArr[i * CC + tid] = wgs;
    // part 2: thread = column c (coalesced within the 256B row segment)
    const float gc = g[tid];
    const int cp = tid ^ bandSW(i);
    for (int o = 0; o < MAXOC; ++o) {
        float wv = w[(size_t)(i * MAXOC + o) * CC + tid];
        wgT2[(size_t)(i * MAXOC + o) * CC + cp] = (o < oc) ? f2bf(wv * gc) : (u16)0;
    }
}

__global__ __launch_bounds__(128) void kbias(const float* __restrict__ partials,
                                             const float* __restrict__ wbArr,
                                             const float* __restrict__ wgsArr,
                                             const float* __restrict__ cb,
                                             float* __restrict__ beff,
                                             float* __restrict__ rstdArr,
                                             int b0, int nb) {
    const int i = blockIdx.x, tid = threadIdx.x;
    __shared__ float lds[4];
    const float wb  = wbArr[i * CC + tid];
    const float wgs = wgsArr[i * CC + tid];
    const float cbo = cb[i * MAXOC + tid];
    for (int bl = 0; bl < nb; ++bl) {
        int b = b0 + bl;
        float s = 0.f, sq = 0.f;
        for (int ch = tid; ch < 250; ch += 128) {
            float2 p = *(const float2*)&partials[((size_t)(b * NB + i) * 250 + ch) * 2];
            s += p.x; sq += p.y;
        }
        #pragma unroll
        for (int off = 1; off < 64; off <<= 1) {
            s  += __shfl_xor(s, off);
            sq += __shfl_xor(sq, off);
        }
        if ((tid & 63) == 0) {
            lds[(tid >> 6) * 2]     = s;
            lds[(tid >> 6) * 2 + 1] = sq;
        }
        __syncthreads();
        s = lds[0] + lds[2];
        sq = lds[1] + lds[3];
        float mean = s * (1.f / 128000.f);
        float var = sq * (1.f / 128000.f) - mean * mean;
        float rstd = rsqrtf(var + 1e-8f);
        beff[(size_t)(b * NB + i) * MAXOC + tid] = cbo + wb - mean * rstd * wgs;
        if (tid == 0) rstdArr[b * NB + i] = rstd;
        __syncthreads();
    }
}

// kmm v2: MFMA 16x16x32 bf16. A = Wgamma[band][oc][cpos], B = X from xt[band][t][cpos].
// Both operands carry the same per-band K permutation -> dot product unchanged.
// C/D mapping (m89-verified): col = lane&15 (t), row = (lane>>4)*4 + reg (oc).
template <int ROWS, int WM, int WN, int RF, int CF, int TSTEP, int NSTEPS, int BCLASS>
__global__ __launch_bounds__(256) void kmmf(const u16* __restrict__ xt,
                                            const u16* __restrict__ wgT2,
                                            const float* __restrict__ beff,
                                            const float* __restrict__ rstdArr,
                                            const float* __restrict__ ctxr,
                                            const float* __restrict__ ctxi,
                                            float* __restrict__ out,
                                            int b0, long long outSize) {
    const int bx = blockIdx.x, by = blockIdx.y, bl = blockIdx.z;
    const int b = b0 + bl;
    const int i = (BCLASS == 0) ? (by < 10 ? by : 30) : (BCLASS == 1 ? 10 + by : 22 + by);
    const int tid = threadIdx.x;
    const int w = tid >> 6, l = tid & 63;
    const int wm = w % WM, wn = w / WM;
    const int RB = wm * 16 * RF;          // wave row base
    const int CB = wn * 16 * CF;          // wave col base (within t-step)
    const int lr = l & 15, lk = l >> 4;

    __shared__ float Y[ROWS][TSTEP + 1];
    __shared__ float bo[ROWS];

    for (int n = tid; n < ROWS; n += 256) bo[n] = beff[(size_t)(b * NB + i) * MAXOC + n];
    const float rstd = rstdArr[b * NB + i];

    // A fragments in registers (persist across t-steps)
    const uint4* wb4 = (const uint4*)(wgT2 + (size_t)i * MAXOC * CC);
    bf16x8 a[RF][4];
    #pragma unroll
    for (int rf = 0; rf < RF; ++rf)
        #pragma unroll
        for (int ks = 0; ks < 4; ++ks)
            a[rf][ks] = __builtin_bit_cast(bf16x8,
                wb4[((RB + rf * 16 + lr) * CC + lk * 8 + ks * 32) >> 3]);

    const uint4* xb4 = (const uint4*)(xt + (size_t)(bl * NB + i) * TPAD * CC);
    const int bw = bandBW(i), F0 = bandF0(i);

    for (int st = 0; st < NSTEPS; ++st) {
        const int t0 = (bx * NSTEPS + st) * TSTEP;
        __syncthreads();   // Y free (prev epilogue done); also covers bo on st=0

        // B fragments (direct from global; L1-resident across waves)
        bf16x8 bf[CF][4];
        #pragma unroll
        for (int cf = 0; cf < CF; ++cf)
            #pragma unroll
            for (int ks = 0; ks < 4; ++ks)
                bf[cf][ks] = __builtin_bit_cast(bf16x8,
                    xb4[((size_t)(t0 + CB + cf * 16 + lr) * CC + lk * 8 + ks * 32) >> 3]);

        f32x4 acc[RF][CF];
        #pragma unroll
        for (int rf = 0; rf < RF; ++rf)
            #pragma unroll
            for (int cf = 0; cf < CF; ++cf)
                acc[rf][cf] = (f32x4){0.f, 0.f, 0.f, 0.f};

        #pragma unroll
        for (int ks = 0; ks < 4; ++ks)
            #pragma unroll
            for (int rf = 0; rf < RF; ++rf)
                #pragma unroll
                for (int cf = 0; cf < CF; ++cf)
                    acc[rf][cf] = __builtin_amdgcn_mfma_f32_16x16x32_bf16(
                        a[rf][ks], bf[cf][ks], acc[rf][cf], 0, 0, 0);

        // scale + bias + relu -> Y
        #pragma unroll
        for (int rf = 0; rf < RF; ++rf)
            #pragma unroll
            for (int cf = 0; cf < CF; ++cf)
                #pragma unroll
                for (int r = 0; r < 4; ++r) {
                    int row = RB + rf * 16 + lk * 4 + r;
                    float v = rstd * acc[rf][cf][r] + bo[row];
                    Y[row][CB + cf * 16 + lr] = fmaxf(v, 0.f);
                }
        __syncthreads();

        // GLU + complex mask; REAL plane only, guarded
        const int jobs = 2 * bw * TSTEP;
        for (int n = tid; n < jobs; n += 256) {
            int tl = n % TSTEP, sf = n / TSTEP;
            int s = sf / bw, f = sf - s * bw;
            int t = t0 + tl;
            if (t < TT_) {
                float lrv = Y[s * bw + f][tl];
                float liv = Y[2 * bw + s * bw + f][tl];
                float grv = Y[4 * bw + s * bw + f][tl];
                float giv = Y[6 * bw + s * bw + f][tl];
                float mr = lrv * (1.f / (1.f + __expf(-grv)));
                float mi = liv * (1.f / (1.f + __expf(-giv)));
                size_t cidx = ((size_t)(i * BB + b) * MAXBW + f) * TT_ + t;
                float cr = ctxr[cidx], ci = ctxi[cidx];
                long long ridx = ((long long)((b * 2 + s) * 257 + F0 + f)) * TT_ + t;
                if (ridx < outSize) out[ridx] = cr * mr - ci * mi;
            }
        }
    }
}

// ==================== FALLBACK (proven in round 6; zero workspace) ====================
template <int ROWS, int RPT, int BCLASS>
__global__ __launch_bounds__(256) void kreal(const float* __restrict__ x,
                                             const float* __restrict__ ctxr,
                                             const float* __restrict__ ctxi,
                                             const float* __restrict__ gamma,
                                             const float* __restrict__ beta,
                                             const float* __restrict__ w,
                                             const float* __restrict__ cb,
                                             float* __restrict__ out,
                                             long long outSize) {
    constexpr int TCH = 64, TPT = 4;
    const int by = blockIdx.x, b = blockIdx.y;
    const int i = (BCLASS == 0) ? (by < 10 ? by : 30) : (BCLASS == 1 ? 10 + by : 22 + by);
    const int tid = threadIdx.x, tx = tid & 15, ty = tid >> 4;

    __shared__ float XN[CC][TCH];
    __shared__ float WT[16][ROWS];
    __shared__ float gl[CC], bt[CC];
    __shared__ float red[8];

    const float* xb = x + (size_t)b * CC * TT_ * NB + i;

    if (tid < CC) { gl[tid] = gamma[i * CC + tid]; bt[tid] = beta[i * CC + tid]; }

    float s = 0.f, sq = 0.f;
    for (int n = tid; n < CC * TT_; n += 256) {
        float v = xb[(size_t)n * NB];
        s += v; sq += v * v;
    }
    #pragma unroll
    for (int off = 1; off < 64; off <<= 1) {
        s  += __shfl_xor(s, off);
        sq += __shfl_xor(sq, off);
    }
    if ((tid & 63) == 0) { red[(tid >> 6) * 2] = s; red[(tid >> 6) * 2 + 1] = sq; }
    __syncthreads();
    s  = red[0] + red[2] + red[4] + red[6];
    sq = red[1] + red[3] + red[5] + red[7];
    const float mean = s * (1.f / 128000.f);
    const float var  = sq * (1.f / 128000.f) - mean * mean;
    const float rstd = rsqrtf(var + 1e-8f);

    const int bw = bandBW(i), F0 = bandF0(i);
    const float* wband = w + (size_t)i * MAXOC * CC;

    for (int t0 = 0; t0 < TT_; t0 += TCH) {
        __syncthreads();
        for (int n = tid; n < CC * TCH; n += 256) {
            int c = n / TCH, tl = n % TCH;
            int t = t0 + tl;
            float v = (t < TT_) ? xb[((size_t)c * TT_ + t) * NB] : 0.f;
            XN[c][tl] = (v - mean) * rstd * gl[c] + bt[c];
        }

        float acc[RPT][TPT];
        #pragma unroll
        for (int r = 0; r < RPT; ++r)
            #pragma unroll
            for (int q = 0; q < TPT; ++q) acc[r][q] = 0.f;

        for (int k0 = 0; k0 < CC; k0 += 16) {
            for (int n = tid; n < 16 * ROWS; n += 256) {
                int kk = n / ROWS, o = n % ROWS;
                WT[kk][o] = wband[(size_t)o * CC + (k0 + kk)];
            }
            __syncthreads();
            #pragma unroll
            for (int kk = 0; kk < 16; ++kk) {
                float wv[RPT], xv[TPT];
                #pragma unroll
                for (int r = 0; r < RPT; ++r) wv[r] = WT[kk][ty * RPT + r];
                #pragma unroll
                for (int q = 0; q < TPT; ++q) xv[q] = XN[k0 + kk][tx * TPT + q];
                #pragma unroll
                for (int r = 0; r < RPT; ++r)
                    #pragma unroll
                    for (int q = 0; q < TPT; ++q) acc[r][q] = fmaf(wv[r], xv[q], acc[r][q]);
            }
            __syncthreads();
        }

        float* Yb = &XN[0][0];
        #pragma unroll
        for (int r = 0; r < RPT; ++r) {
            int o = ty * RPT + r;
            float bv = cb[i * MAXOC + o];
            #pragma unroll
            for (int q = 0; q < TPT; ++q)
                Yb[o * TCH + tx * TPT + q] = fmaxf(acc[r][q] + bv, 0.f);
        }
        __syncthreads();

        const int jobs = 2 * bw * TCH;
        for (int n = tid; n < jobs; n += 256) {
            int tl = n % TCH, sf = n / TCH;
            int ss = sf / bw, f = sf - ss * bw;
            int t = t0 + tl;
            if (t < TT_) {
                float lrv = Yb[(ss * bw + f) * TCH + tl];
                float liv = Yb[(2 * bw + ss * bw + f) * TCH + tl];
                float grv = Yb[(4 * bw + ss * bw + f) * TCH + tl];
                float giv = Yb[(6 * bw + ss * bw + f) * TCH + tl];
                float mr = lrv * (1.f / (1.f + __expf(-grv)));
                float mi = liv * (1.f / (1.f + __expf(-giv)));
                size_t cidx = ((size_t)(i * BB + b) * MAXBW + f) * TT_ + t;
                float cr = ctxr[cidx], ci = ctxi[cidx];
                long long ridx = ((long long)((b * 2 + ss) * 257 + F0 + f)) * TT_ + t;
                if (ridx < outSize) out[ridx] = cr * mr - ci * mi;
            }
        }
    }
}

extern "C" void kernel_launch(void* const* d_in, const int* in_sizes, int n_in,
                              void* d_out, int out_size, void* d_ws, size_t ws_size,
                              hipStream_t stream) {
    const float* sep   = (const float*)d_in[0];
    const float* ctxr  = (const float*)d_in[2];
    const float* ctxi  = (const float*)d_in[3];
    const float* gamma = (const float*)d_in[4];
    const float* beta  = (const float*)d_in[5];
    const float* convw = (const float*)d_in[6];
    const float* convb = (const float*)d_in[7];
    float* out = (float*)d_out;

    long long outSize = (long long)out_size;   // real plane, strictly guarded

    const size_t fixedEnd = 1671936;
    const size_t perB = (size_t)NB * TPAD * CC * 2;   // 8,126,464 B per batch

    if (ws_size >= fixedEnd + perB) {
        char* ws = (char*)d_ws;
        float* partials = (float*)(ws + 0);          // 8*31*250*2*4 = 496,000 B
        float* rstdArr  = (float*)(ws + 496128);
        float* wbArr    = (float*)(ws + 497408);
        float* wgsArr   = (float*)(ws + 513280);
        float* beff     = (float*)(ws + 529152);     // 126,976 B
        u16*   wgT2     = (u16*)(ws + 656128);       // 31*128*128*2 = 1,015,808 B
        u16*   xt       = (u16*)(ws + 1671936);

        int nbper = (int)((ws_size - fixedEnd) / perB);
        if (nbper > BB) nbper = BB;

        kfoldW<<<dim3(NB), 128, 0, stream>>>(convw, gamma, beta, wgT2, wbArr, wgsArr);

        for (int b0 = 0; b0 < BB; b0 += nbper) {
            int nb = (BB - b0 < nbper) ? (BB - b0) : nbper;
            kstat<<<dim3(250, nb), 256, 0, stream>>>(sep, xt, partials, b0);
            kbias<<<dim3(NB), 128, 0, stream>>>(partials, wbArr, wgsArr, convb, beff, rstdArr, b0, nb);
            // class A: oc=24 (pad 32), bands {0..9,30}: ROWS=32, WM=2, WN=2, TSTEP=128
            kmmf<32, 2, 2, 1, 4, 128, 2, 0><<<dim3(4, 11, nb), 256, 0, stream>>>(xt, wgT2, beff, rstdArr, ctxr, ctxi, out, b0, outSize);
            // class B: oc=64, bands 10..21: ROWS=64, WM=4, WN=1, TSTEP=64
            kmmf<64, 4, 1, 1, 4, 64, 2, 1><<<dim3(8, 12, nb), 256, 0, stream>>>(xt, wgT2, beff, rstdArr, ctxr, ctxi, out, b0, outSize);
            // class C: oc=128, bands 22..29: ROWS=128, WM=4, WN=1, RF=2, TSTEP=64
            kmmf<128, 4, 1, 2, 4, 64, 2, 2><<<dim3(8, 8, nb), 256, 0, stream>>>(xt, wgT2, beff, rstdArr, ctxr, ctxi, out, b0, outSize);
        }
    } else {
        kreal<32, 2, 0><<<dim3(11, BB), 256, 0, stream>>>(sep, ctxr, ctxi, gamma, beta, convw, convb, out, outSize);
        kreal<64, 4, 1><<<dim3(12, BB), 256, 0, stream>>>(sep, ctxr, ctxi, gamma, beta, convw, convb, out, outSize);
        kreal<128, 8, 2><<<dim3(8, BB), 256, 0, stream>>>(sep, ctxr, ctxi, gamma, beta, convw, convb, out, outSize);
    }
}